// Round 2
// baseline (125.201 us; speedup 1.0000x reference)
//
#include <hip/hip_runtime.h>

// Depthwise cross-correlation: z (64,256,7,7) over x (64,256,31,31) VALID
// -> out (64,256,25,25), scaled 0.001. fp32 end-to-end.
//
// Round 9: persistent waves + per-wave LDS double-buffer + counted vmcnt.
//   R8 post-mortem: zero-barrier wave pipeline was NEUTRAL (~37.5us). Cause:
//   each wave front-loads ALL its HBM traffic then computes then retires, so
//   new loads enter a CU only when an LDS slot frees -> blocks cycle in
//   bunches -> CU alternates [all-load ~6.5us][all-compute ~12us]: serial sum
//   HBM(17.3) + VALU(9) + DS(10.5) = 37us. Matches both R7 and R8 exactly.
//   Fix: grid = 1280 blocks (5/CU, 32KB LDS, fully resident). Each wave
//   grid-strides over 3-4 slice-pairs with TWO 8KB buffers: compute pair p
//   from buf A while pair p+2560 streams into buf B (8 gl_lds in flight per
//   wave at all times -> ~80KB/CU >> 9KB Little's-law need for 6.3TB/s).
//   Loop-top wait is s_waitcnt vmcnt(8) -- NEVER 0 -- so next-pair loads
//   span the compute phase; out-stores drain lazily under compute.
//   lgkmcnt(0) before re-staging a buffer closes the ds_read vs gl_lds-
//   return race (DS-queue delay could exceed the ~300cy load return).

#define KH 7
#define KW 7
#define XH 31
#define XW 31
#define OH 25
#define OW 25
#define NSLICE (64 * 256)
#define THREADS 128
#define NPAIR (NSLICE / 2)            // 8192 slice-pairs
#define NBLK 1280                     // 5 blocks/CU x 256 CU, all resident
#define NWAVE (NBLK * 2)              // 2560 waves; 3-4 pairs per wave
#define BUF_DW 2048                   // per-buffer dwords: pre + 2*961 <= 1925
#define SLICE_X (XH * XW)             // 961
#define SLICE_O (OH * OW)             // 625
#define X_TOTAL_DW (NSLICE * SLICE_X)

__device__ __forceinline__ void gl_lds16(const float* g, float* l) {
    __builtin_amdgcn_global_load_lds(
        (const __attribute__((address_space(1))) void*)g,
        (__attribute__((address_space(3))) void*)l, 16, 0, 0);
}

// Stage one slice-pair (1922 dwords + slack) as 8 x (64 lanes x 16 B).
__device__ __forceinline__ void stage_pair(const float* __restrict__ x,
                                           float* __restrict__ buf,
                                           int pair, int lane) {
    const int g0r = pair * (2 * SLICE_X);
    const int g0  = g0r - (g0r & 3);          // 16B-aligned base, slack in [0,3]
    #pragma unroll
    for (int k = 0; k < 8; ++k) {
        const int dw  = k * 256 + lane * 4;
        const int gdw = min(g0 + dw, X_TOTAL_DW - 4);   // clamp: last pair only
        gl_lds16(x + gdw, buf + dw);
    }
}

// Compute slice s (0/1) of the pair in buf; stage scaled output into
// buf[s*625 .. s*625+625) (x there is already consumed by read order).
__device__ __forceinline__ void compute_slice(float* __restrict__ buf,
                                              const float* __restrict__ zsl,
                                              int pre, int s,
                                              int oy, int c0, bool act) {
    float wz[KH * KW];
    #pragma unroll
    for (int t = 0; t < KH * KW; ++t) wz[t] = zsl[t];   // wave-uniform
    if (act) {
        float acc[13] = {};
        const float* __restrict__ xrow = buf + pre + s * SLICE_X;
        #pragma unroll
        for (int i = 0; i < KH; ++i) {
            const float* __restrict__ p = xrow + (oy + i) * XW + c0;
            float f[19];                       // h=1 max index c+j = 18
            #pragma unroll
            for (int c = 0; c < 19; ++c) f[c] = p[c];
            #pragma unroll
            for (int j = 0; j < KW; ++j) {
                const float w = wz[i * KW + j];
                #pragma unroll
                for (int c = 0; c < 13; ++c)
                    acc[c] = fmaf(f[c + j], w, acc[c]);
            }
        }
        const int fb = s * SLICE_O + oy * OW + c0;
        #pragma unroll
        for (int c = 0; c < 12; ++c) buf[fb + c] = acc[c] * 0.001f;
        if (c0 == 0) buf[fb + 12] = acc[12] * 0.001f;   // h=0 owns 13th col
    }
}

__global__ __launch_bounds__(THREADS, 4)
void xcorr_dw_kernel(const float* __restrict__ z,
                     const float* __restrict__ x,
                     float* __restrict__ out) {
    __shared__ float xs[2][2][BUF_DW];        // [wave][buf] : 32 KB/block
    const int tid  = threadIdx.x;
    const int lane = tid & 63;
    const int wv   = __builtin_amdgcn_readfirstlane(tid >> 6);
    const int wid  = blockIdx.x * 2 + wv;     // wave id in [0, NWAVE)

    // lane -> (col-half h, row oy); 50/64 lanes active in compute
    const int h   = (lane >= OH) ? 1 : 0;
    const int oy  = h ? (lane - OH) : lane;
    const int c0  = h ? 13 : 0;               // h=0: cols 0..12, h=1: 13..24
    const bool act = (lane < 2 * OH);

    float* b0 = xs[wv][0];
    float* b1 = xs[wv][1];

    // Prologue: fill the 2-deep pipeline (16 loads in flight).
    stage_pair(x, b0, wid, lane);                                  // wid < 8192 always
    if (wid + NWAVE < NPAIR) stage_pair(x, b1, wid + NWAVE, lane);

    #pragma unroll 1
    for (int p = wid; p < NPAIR; p += NWAVE) {
        // Counted wait: all but the 8 newest VMEM ops retired ->
        // current buffer's loads (and previous pair's stores) are done,
        // while the NEXT pair's 8 loads keep flying.
        asm volatile("s_waitcnt vmcnt(8)" ::: "memory");
        __builtin_amdgcn_sched_barrier(0);

        const int wslice = 2 * p;
        const int pre    = (2 * p) & 3;       // (pair*1922) & 3
        const float* __restrict__ zp = z + (size_t)wslice * (KH * KW);

        compute_slice(b0, zp,           pre, 0, oy, c0, act);
        compute_slice(b0, zp + KH * KW, pre, 1, oy, c0, act);

        // Coalesced copy: 1250 dwords = 19 x 64 + 34 tail.
        float* __restrict__ og = out + (size_t)wslice * SLICE_O;
        #pragma unroll
        for (int k = 0; k < 19; ++k) og[k * 64 + lane] = b0[k * 64 + lane];
        if (lane < 2 * SLICE_O - 19 * 64) og[19 * 64 + lane] = b0[19 * 64 + lane];

        // Drain DS reads before gl_lds may overwrite this buffer, then
        // issue the pair-after-next into the just-freed buffer.
        asm volatile("s_waitcnt lgkmcnt(0)" ::: "memory");
        __builtin_amdgcn_sched_barrier(0);
        if (p + 2 * NWAVE < NPAIR) stage_pair(x, b0, p + 2 * NWAVE, lane);

        float* t = b0; b0 = b1; b1 = t;       // swap buffers
    }
}

extern "C" void kernel_launch(void* const* d_in, const int* in_sizes, int n_in,
                              void* d_out, int out_size, void* d_ws, size_t ws_size,
                              hipStream_t stream) {
    const float* z = (const float*)d_in[0];   // (64,256,7,7)
    const float* x = (const float*)d_in[1];   // (64,256,31,31)
    float* out = (float*)d_out;               // (64,256,25,25)
    xcorr_dw_kernel<<<dim3(NBLK), dim3(THREADS), 0, stream>>>(z, x, out);
}

// Round 3
// 116.248 us; speedup vs baseline: 1.0770x; 1.0770x over previous
//
#include <hip/hip_runtime.h>

// Depthwise cross-correlation: z (64,256,7,7) over x (64,256,31,31) VALID
// -> out (64,256,25,25), scaled 0.001. fp32 end-to-end.
//
// Round 10: single-slice double-buffer, 20 waves/CU, store-safe counted vmcnt.
//   R9 post-mortem (first kernel-visible counters: 63us, VALU 19.5%, HBM
//   14.5%, occ 16%): 16KB/wave buffers halved TLP to 10 waves/CU, and the
//   loop-top vmcnt(8) drained all 20 in-order-older output stores every
//   iteration (full store round-trip exposed per wave per iter).
//   Fix: buffer = ONE slice (4KB; pre+961<=964 dw). 8KB/wave -> 16KB/block
//   -> 10 blocks/CU = 20 waves/CU (R8's TLP) with R9's pipelining intent.
//   Per iter VMEM = 10 stores + 4 loads = 14 ALWAYS (tail iters stage a
//   dummy slice-0 to preserve the count). Loop-top s_waitcnt vmcnt(14):
//   in-order retire => current buffer's loads (14 ops old) are done, with
//   zero store draining and the next slice's 4 loads still in flight.
//   Peeled iter 0 waits vmcnt(4). lgkmcnt(0) sits only between the copy-out
//   ds_reads and the gl_lds re-stage (data-dep already forces most of it).
//   Final vmcnt(0) protects successor blocks' LDS from in-flight dummy loads.

#define KH 7
#define KW 7
#define XW 31
#define OH 25
#define OW 25
#define NSLICE (64 * 256)
#define THREADS 128
#define NBLK 2560                     // 10 blocks/CU x 256 CU, persistent
#define NWAVES (NBLK * 2)             // 5120 waves; 3-4 slices per wave
#define BUF_DW 1024                   // 4 KB: pre + 961 <= 964
#define SLICE_X (XW * XW)             // 961
#define SLICE_O (OH * OW)             // 625
#define X_TOTAL_DW (NSLICE * SLICE_X) // 15,745,024

__device__ __forceinline__ void gl_lds16(const float* g, float* l) {
    __builtin_amdgcn_global_load_lds(
        (const __attribute__((address_space(1))) void*)g,
        (__attribute__((address_space(3))) void*)l, 16, 0, 0);
}

// Stage one slice (961 dwords + align slack) as 4 x (64 lanes x 16 B).
__device__ __forceinline__ void stage_slice(const float* __restrict__ x,
                                            float* __restrict__ buf,
                                            int slice, int lane) {
    const int g0 = (slice * SLICE_X) & ~3;        // 16B-aligned, slack in [0,3]
    #pragma unroll
    for (int k = 0; k < 4; ++k) {
        const int dw = k * 256 + lane * 4;
        gl_lds16(x + min(g0 + dw, X_TOTAL_DW - 4), buf + dw);   // clamp: last slice
    }
}

// Compute one slice from buf, stage scaled output into buf[0,625) (x there is
// consumed, same-wave DS order), then coalesced copy to global.
// VMEM issued: exactly 10 stores.
__device__ __forceinline__ void process_slice(float* __restrict__ buf,
                                              const float* __restrict__ z,
                                              float* __restrict__ out,
                                              int slice, int lane,
                                              int oy, int c0, bool act) {
    const int pre = (slice * SLICE_X) & 3;
    const float* __restrict__ zw = z + (size_t)slice * (KH * KW);
    if (act) {
        float acc[13] = {};
        const float* __restrict__ xrow = buf + pre;
        #pragma unroll
        for (int i = 0; i < KH; ++i) {
            const float* __restrict__ p = xrow + (oy + i) * XW + c0;
            float f[19];                           // h=1 touches 1 stray dw: in-bounds, discarded
            #pragma unroll
            for (int c = 0; c < 19; ++c) f[c] = p[c];
            #pragma unroll
            for (int j = 0; j < KW; ++j) {
                const float w = zw[i * KW + j];    // wave-uniform (s_load)
                #pragma unroll
                for (int c = 0; c < 13; ++c)
                    acc[c] = fmaf(f[c + j], w, acc[c]);
            }
        }
        const int fb = oy * OW + c0;
        #pragma unroll
        for (int c = 0; c < 12; ++c) buf[fb + c] = acc[c] * 0.001f;
        if (c0 == 0) buf[fb + 12] = acc[12] * 0.001f;   // h=0 owns col 12
    }
    // Coalesced copy: 625 dwords = 9 x 64 + 49 tail -> 10 store instrs.
    float* __restrict__ og = out + (size_t)slice * SLICE_O;
    #pragma unroll
    for (int k = 0; k < 9; ++k) og[k * 64 + lane] = buf[k * 64 + lane];
    if (lane < SLICE_O - 576) og[576 + lane] = buf[576 + lane];
}

__global__ __launch_bounds__(THREADS, 5)
void xcorr_dw_kernel(const float* __restrict__ z,
                     const float* __restrict__ x,
                     float* __restrict__ out) {
    __shared__ float xs[2][2][BUF_DW];            // [wave][buf]: 16 KB/block
    const int lane = threadIdx.x & 63;
    const int wv   = __builtin_amdgcn_readfirstlane(threadIdx.x >> 6);
    const int wid  = blockIdx.x * 2 + wv;         // wave id in [0, NWAVES)

    // lane -> (col-half h, row oy); 50/64 lanes active in compute
    const int h   = (lane >= OH) ? 1 : 0;
    const int oy  = h ? lane - OH : lane;
    const int c0  = h ? 13 : 0;                   // h=0: cols 0..12, h=1: 13..24
    const bool act = (lane < 2 * OH);

    float* bcur = xs[wv][0];
    float* bnxt = xs[wv][1];

    // Prologue: 2-deep pipeline (8 loads in flight). wid+NWAVES < 10240 < NSLICE.
    stage_slice(x, bcur, wid, lane);
    stage_slice(x, bnxt, wid + NWAVES, lane);

    // ---- iteration 0 (peeled): only bnxt's 4 loads may stay outstanding.
    asm volatile("s_waitcnt vmcnt(4)" ::: "memory");
    __builtin_amdgcn_sched_barrier(0);
    process_slice(bcur, z, out, wid, lane, oy, c0, act);
    asm volatile("s_waitcnt lgkmcnt(0)" ::: "memory");   // copy reads done before re-stage
    __builtin_amdgcn_sched_barrier(0);
    {
        const int s2 = wid + 2 * NWAVES;
        stage_slice(x, bcur, s2 < NSLICE ? s2 : 0, lane);   // dummy keeps vmcnt invariant
    }
    { float* t = bcur; bcur = bnxt; bnxt = t; }

    // ---- steady state: every iter issued exactly 10 stores + 4 loads after
    // the current buffer's loads -> vmcnt(14) proves them retired, drains
    // nothing newer (stores + next loads keep flying).
    #pragma unroll 1
    for (int p = wid + NWAVES; p < NSLICE; p += NWAVES) {
        asm volatile("s_waitcnt vmcnt(14)" ::: "memory");
        __builtin_amdgcn_sched_barrier(0);
        process_slice(bcur, z, out, p, lane, oy, c0, act);
        asm volatile("s_waitcnt lgkmcnt(0)" ::: "memory");
        __builtin_amdgcn_sched_barrier(0);
        const int s2 = p + 2 * NWAVES;
        stage_slice(x, bcur, s2 < NSLICE ? s2 : 0, lane);
        float* t = bcur; bcur = bnxt; bnxt = t;
    }

    // Drain in-flight gl_lds before workgroup teardown (LDS could be reused).
    asm volatile("s_waitcnt vmcnt(0)" ::: "memory");
}

extern "C" void kernel_launch(void* const* d_in, const int* in_sizes, int n_in,
                              void* d_out, int out_size, void* d_ws, size_t ws_size,
                              hipStream_t stream) {
    const float* z = (const float*)d_in[0];   // (64,256,7,7)
    const float* x = (const float*)d_in[1];   // (64,256,31,31)
    float* out = (float*)d_out;               // (64,256,25,25)
    xcorr_dw_kernel<<<dim3(NBLK), dim3(THREADS), 0, stream>>>(z, x, out);
}